// Round 6
// baseline (209.363 us; speedup 1.0000x reference)
//
#include <hip/hip_runtime.h>
#include <math.h>

// Problem: B=64, T=512, D=1024.
//   v[b,d]     = sum_e W[d,e] * x[b,T-1,e]
//   scores[b,t]= sum_d x[b,t,d] * v[b,d]          (t in 0..510)
//   alpha      = softmax_t(scores)
//   c[b,d]     = sum_t alpha[b,t] * x[b,t,d]
//   out[b]     = concat(c[b,:], x[b,T-1,:])       (64 x 2048 fp32)

#define BB 64
#define TT 512
#define DD 1024
#define TH 511           // valid history rows: 0..510
#define GROUPS 16        // blocks per batch
#define RPW 8            // rows per wave (4 waves * 8 = 32 rows per block)

// workspace (floats):
//   v      : [BB][DD]          off 0
//   partC  : [BB][GROUPS][DD]  off 65536
//   partML : [BB][GROUPS][2]   off 1114112
//   cnt    : [BB] ints         off 1116160

__device__ __forceinline__ float dot16(const float4* a, const float4* b) {
    float s = 0.f;
#pragma unroll
    for (int j = 0; j < 4; ++j)
        s += a[j].x * b[j].x + a[j].y * b[j].y + a[j].z * b[j].z + a[j].w * b[j].w;
    return s;
}

// ---------------- kernel 1: v = x_last @ W^T (+ zero finalize counters) ----
// 256 blocks x 4 waves; wave = 4 d-rows x 16 batches, batches in pairs (ILP 8).
// launch_bounds (256,4): VGPR cap 128; uses ~112 (w4 64 + xA/xB 32 + misc).
__global__ __launch_bounds__(256, 4) void k_v(const float* __restrict__ x,
                                              const float* __restrict__ W,
                                              float* __restrict__ v,
                                              int* __restrict__ cnt) {
    if (blockIdx.x == 0 && threadIdx.x < BB) cnt[threadIdx.x] = 0;

    const int wave = threadIdx.x >> 6;
    const int lane = threadIdx.x & 63;
    const int wg   = blockIdx.x * 4 + wave;   // 0..1023
    const int d0   = (wg >> 2) * 4;           // 256 d-quads
    const int bg   = wg & 3;                  // 4 batch-groups of 16

    float4 w4[4][4];
#pragma unroll
    for (int k = 0; k < 4; ++k)
#pragma unroll
        for (int j = 0; j < 4; ++j)
            w4[k][j] = *(const float4*)(W + (size_t)(d0 + k) * DD + j * 256 + lane * 4);

    float res = 0.f;                          // lane l -> (b = bg*16+(l>>2), d = d0+(l&3))
#pragma unroll
    for (int ip = 0; ip < 8; ++ip) {
        const int i0 = ip * 2;
        const float* xl0 = x + ((size_t)(bg * 16 + i0) * TT + (TT - 1)) * DD;
        const float* xl1 = xl0 + (size_t)TT * DD;
        float4 xA[4], xB[4];
#pragma unroll
        for (int j = 0; j < 4; ++j) {
            xA[j] = *(const float4*)(xl0 + j * 256 + lane * 4);
            xB[j] = *(const float4*)(xl1 + j * 256 + lane * 4);
        }
        float pA[4], pB[4];
#pragma unroll
        for (int k = 0; k < 4; ++k) {
            pA[k] = dot16(w4[k], xA);
            pB[k] = dot16(w4[k], xB);
        }
#pragma unroll
        for (int mm = 1; mm < 64; mm <<= 1) {
#pragma unroll
            for (int k = 0; k < 4; ++k) {
                pA[k] += __shfl_xor(pA[k], mm, 64);
                pB[k] += __shfl_xor(pB[k], mm, 64);
            }
        }
#pragma unroll
        for (int k = 0; k < 4; ++k) {
            if (lane == i0 * 4 + k)       res = pA[k];
            if (lane == (i0 + 1) * 4 + k) res = pB[k];
        }
    }
    v[(size_t)(bg * 16 + (lane >> 2)) * DD + d0 + (lane & 3)] = res;
}

// ---------------- kernel 2: wave-autonomous flash + fused finalize ---------
// 1024 blocks (64 b x 16 groups), 256 thr, (256,4) -> VGPR cap 128 (~115 used,
// NO spill — R5 regression was compiler choosing 64 VGPR without min-waves).
// Wave: 8 rows in pairs, online softmax in registers, pair double-buffer,
// no barriers in hot loop. Last block per batch combines 16 partials.
__global__ __launch_bounds__(256, 4) void k_chunk(const float* __restrict__ x,
                                                  const float* __restrict__ v,
                                                  float* __restrict__ partC,
                                                  float* __restrict__ partML,
                                                  int* __restrict__ cnt,
                                                  float* __restrict__ out) {
    __shared__ float cw[4][DD];               // 16 KB combine buffer
    __shared__ float cml[4][2];
    __shared__ float sm[GROUPS], sl[GROUPS];
    __shared__ int   done;

    const int b    = blockIdx.x >> 4;
    const int g    = blockIdx.x & (GROUPS - 1);
    const int wave = threadIdx.x >> 6;
    const int lane = threadIdx.x & 63;
    const int r0   = g * 32 + wave * RPW;     // <= 504
    const int col  = lane * 4;

    const float* xb = x + (size_t)b * TT * DD;

    float4 v4[4];
#pragma unroll
    for (int j = 0; j < 4; ++j)
        v4[j] = *(const float4*)(v + (size_t)b * DD + j * 256 + col);

#define LOADROW(dst, r) do { const float* _p = xb + (size_t)(r) * DD + col;   \
        dst[0] = *(const float4*)(_p);       dst[1] = *(const float4*)(_p + 256); \
        dst[2] = *(const float4*)(_p + 512); dst[3] = *(const float4*)(_p + 768); } while (0)

    float4 bA[4], bB[4], bC[4], bD[4];
    LOADROW(bA, r0);
    LOADROW(bB, r0 + 1);

    float m = -INFINITY, l = 0.f;
    float4 acc[4] = {make_float4(0,0,0,0), make_float4(0,0,0,0),
                     make_float4(0,0,0,0), make_float4(0,0,0,0)};

#pragma unroll
    for (int p = 0; p < 4; ++p) {
        float4* ca = (p & 1) ? bC : bA;
        float4* cb = (p & 1) ? bD : bB;
        float4* na = (p & 1) ? bA : bC;
        float4* nb = (p & 1) ? bB : bD;
        if (p < 3) {                          // prefetch next pair (clamped)
            LOADROW(na, min(r0 + 2 * p + 2, TH - 1));
            LOADROW(nb, min(r0 + 2 * p + 3, TH - 1));
        }
        float s0 = dot16(v4, ca);
        float s1 = dot16(v4, cb);
#pragma unroll
        for (int mm = 1; mm < 64; mm <<= 1) {
            s0 += __shfl_xor(s0, mm, 64);
            s1 += __shfl_xor(s1, mm, 64);
        }
        if (r0 + 2 * p     >= TH) s0 = -INFINITY;   // only possible in last pair
        if (r0 + 2 * p + 1 >= TH) s1 = -INFINITY;

        const float mn = fmaxf(m, fmaxf(s0, s1));
        if (mn > m) {                         // wave-uniform (butterfly output)
            const float sc = __expf(m - mn);  // first pair: exp(-inf)=0
#pragma unroll
            for (int j = 0; j < 4; ++j) {
                acc[j].x *= sc; acc[j].y *= sc; acc[j].z *= sc; acc[j].w *= sc;
            }
            l *= sc;
            m = mn;
        }
        const float e0 = __expf(s0 - m);
        const float e1 = __expf(s1 - m);
        l += e0 + e1;
#pragma unroll
        for (int j = 0; j < 4; ++j) {
            acc[j].x += e0 * ca[j].x + e1 * cb[j].x;
            acc[j].y += e0 * ca[j].y + e1 * cb[j].y;
            acc[j].z += e0 * ca[j].z + e1 * cb[j].z;
            acc[j].w += e0 * ca[j].w + e1 * cb[j].w;
        }
    }
#undef LOADROW

    // one cross-wave combine per block
#pragma unroll
    for (int j = 0; j < 4; ++j)
        *(float4*)(&cw[wave][j * 256 + col]) = acc[j];
    if (lane == 0) { cml[wave][0] = m; cml[wave][1] = l; }
    __syncthreads();

    const float M = fmaxf(fmaxf(cml[0][0], cml[1][0]), fmaxf(cml[2][0], cml[3][0]));
    const float w0 = __expf(cml[0][0] - M), w1 = __expf(cml[1][0] - M);
    const float w2 = __expf(cml[2][0] - M), w3 = __expf(cml[3][0] - M);
    const float L = w0 * cml[0][1] + w1 * cml[1][1] + w2 * cml[2][1] + w3 * cml[3][1];

    const int d0 = threadIdx.x * 4;
    {
        const float4 s0 = *(const float4*)(&cw[0][d0]);
        const float4 s1 = *(const float4*)(&cw[1][d0]);
        const float4 s2 = *(const float4*)(&cw[2][d0]);
        const float4 s3 = *(const float4*)(&cw[3][d0]);
        float4 o;
        o.x = w0 * s0.x + w1 * s1.x + w2 * s2.x + w3 * s3.x;
        o.y = w0 * s0.y + w1 * s1.y + w2 * s2.y + w3 * s3.y;
        o.z = w0 * s0.z + w1 * s1.z + w2 * s2.z + w3 * s3.z;
        o.w = w0 * s0.w + w1 * s1.w + w2 * s2.w + w3 * s3.w;
        *(float4*)(partC + ((size_t)b * GROUPS + g) * DD + d0) = o;
    }
    if (threadIdx.x == 0) {
        partML[((size_t)b * GROUPS + g) * 2 + 0] = M;
        partML[((size_t)b * GROUPS + g) * 2 + 1] = L;
    }
    __threadfence();                          // release partials (device scope)
    __syncthreads();
    if (threadIdx.x == 0) {
        const int r = atomicAdd(&cnt[b], 1);
        done = (r == GROUPS - 1);
    }
    __syncthreads();
    if (!done) return;

    // ---- finalize (last block of this batch) ----
    __threadfence();                          // acquire partials
    if (threadIdx.x < GROUPS) {
        sm[threadIdx.x] = partML[((size_t)b * GROUPS + threadIdx.x) * 2 + 0];
        sl[threadIdx.x] = partML[((size_t)b * GROUPS + threadIdx.x) * 2 + 1];
    }
    __syncthreads();

    float Mg = -INFINITY;
#pragma unroll
    for (int g2 = 0; g2 < GROUPS; ++g2) Mg = fmaxf(Mg, sm[g2]);
    float wgt[GROUPS];
    float Lg = 0.f;
#pragma unroll
    for (int g2 = 0; g2 < GROUPS; ++g2) {
        wgt[g2] = __expf(sm[g2] - Mg);
        Lg += wgt[g2] * sl[g2];
    }
    const float invL = 1.f / Lg;

    float4 a = make_float4(0.f, 0.f, 0.f, 0.f);
#pragma unroll
    for (int g2 = 0; g2 < GROUPS; ++g2) {
        const float4 pc = *(const float4*)(partC + ((size_t)b * GROUPS + g2) * DD + d0);
        a.x += wgt[g2] * pc.x; a.y += wgt[g2] * pc.y;
        a.z += wgt[g2] * pc.z; a.w += wgt[g2] * pc.w;
    }
    a.x *= invL; a.y *= invL; a.z *= invL; a.w *= invL;
    *(float4*)(out + (size_t)b * 2048 + d0) = a;

    const float4 xl = *(const float4*)(xb + (size_t)(TT - 1) * DD + d0);
    *(float4*)(out + (size_t)b * 2048 + 1024 + d0) = xl;
}

extern "C" void kernel_launch(void* const* d_in, const int* in_sizes, int n_in,
                              void* d_out, int out_size, void* d_ws, size_t ws_size,
                              hipStream_t stream) {
    const float* x = (const float*)d_in[0];   // (64,512,1024) fp32
    const float* W = (const float*)d_in[1];   // (1024,1024) fp32
    float* out = (float*)d_out;               // (64,2048) fp32

    float* ws     = (float*)d_ws;
    float* v      = ws;                                           // 65536
    float* partC  = ws + 65536;                                   // 1048576
    float* partML = ws + 65536 + (size_t)BB * GROUPS * DD;        // 2048
    int*   cnt    = (int*)(partML + (size_t)BB * GROUPS * 2);     // 64 ints

    k_v<<<256, 256, 0, stream>>>(x, W, v, cnt);
    k_chunk<<<BB * GROUPS, 256, 0, stream>>>(x, v, partC, partML, cnt, out);
}

// Round 7
// 207.032 us; speedup vs baseline: 1.0113x; 1.0113x over previous
//
#include <hip/hip_runtime.h>
#include <math.h>

// Problem: B=64, T=512, D=1024.
//   v[b,d]     = sum_e W[d,e] * x[b,T-1,e]
//   scores[b,t]= sum_d x[b,t,d] * v[b,d]          (t in 0..510)
//   alpha      = softmax_t(scores)
//   c[b,d]     = sum_t alpha[b,t] * x[b,t,d]
//   out[b]     = concat(c[b,:], x[b,T-1,:])       (64 x 2048 fp32)

#define BB 64
#define TT 512
#define DD 1024
#define TH 511           // valid history rows: 0..510
#define GROUPS 16        // blocks per batch
#define RPW 8            // rows per wave (4 waves * 8 = 32 rows per block)

// workspace (floats):
//   v      : [BB][DD]          off 0
//   partC  : [BB][GROUPS][DD]  off 65536
//   partML : [BB][GROUPS][2]   off 1114112
//   cnt    : [BB] ints         off 1116160

__device__ __forceinline__ float dot16(const float4* a, const float4* b) {
    float s = 0.f;
#pragma unroll
    for (int j = 0; j < 4; ++j)
        s += a[j].x * b[j].x + a[j].y * b[j].y + a[j].z * b[j].z + a[j].w * b[j].w;
    return s;
}

// ---------------- kernel 1: v = x_last @ W^T (+ zero finalize counters) ----
__global__ __launch_bounds__(256, 4) void k_v(const float* __restrict__ x,
                                              const float* __restrict__ W,
                                              float* __restrict__ v,
                                              int* __restrict__ cnt) {
    if (blockIdx.x == 0 && threadIdx.x < BB) cnt[threadIdx.x] = 0;

    const int wave = threadIdx.x >> 6;
    const int lane = threadIdx.x & 63;
    const int wg   = blockIdx.x * 4 + wave;   // 0..1023
    const int d0   = (wg >> 2) * 4;           // 256 d-quads
    const int bg   = wg & 3;                  // 4 batch-groups of 16

    float4 w4[4][4];
#pragma unroll
    for (int k = 0; k < 4; ++k)
#pragma unroll
        for (int j = 0; j < 4; ++j)
            w4[k][j] = *(const float4*)(W + (size_t)(d0 + k) * DD + j * 256 + lane * 4);

    float res = 0.f;                          // lane l -> (b = bg*16+(l>>2), d = d0+(l&3))
#pragma unroll
    for (int ip = 0; ip < 8; ++ip) {
        const int i0 = ip * 2;
        const float* xl0 = x + ((size_t)(bg * 16 + i0) * TT + (TT - 1)) * DD;
        const float* xl1 = xl0 + (size_t)TT * DD;
        float4 xA[4], xB[4];
#pragma unroll
        for (int j = 0; j < 4; ++j) {
            xA[j] = *(const float4*)(xl0 + j * 256 + lane * 4);
            xB[j] = *(const float4*)(xl1 + j * 256 + lane * 4);
        }
        float pA[4], pB[4];
#pragma unroll
        for (int k = 0; k < 4; ++k) {
            pA[k] = dot16(w4[k], xA);
            pB[k] = dot16(w4[k], xB);
        }
#pragma unroll
        for (int mm = 1; mm < 64; mm <<= 1) {
#pragma unroll
            for (int k = 0; k < 4; ++k) {
                pA[k] += __shfl_xor(pA[k], mm, 64);
                pB[k] += __shfl_xor(pB[k], mm, 64);
            }
        }
#pragma unroll
        for (int k = 0; k < 4; ++k) {
            if (lane == i0 * 4 + k)       res = pA[k];
            if (lane == (i0 + 1) * 4 + k) res = pB[k];
        }
    }
    v[(size_t)(bg * 16 + (lane >> 2)) * DD + d0 + (lane & 3)] = res;
}

// ---------------- kernel 2: wave-autonomous flash + fused finalize ---------
// 1024 blocks (64 b x 16 groups), 256 thr. Wave: 8 rows processed in pairs,
// STATIC buffer names only (rule #20: pointer-selected local buffers go to
// scratch -> that was the R5/R6 regression). Depth-2-pair prefetch, no
// barriers in hot loop. Last block per batch combines the 16 partials.
__global__ __launch_bounds__(256, 4) void k_chunk(const float* __restrict__ x,
                                                  const float* __restrict__ v,
                                                  float* __restrict__ partC,
                                                  float* __restrict__ partML,
                                                  int* __restrict__ cnt,
                                                  float* __restrict__ out) {
    __shared__ float cw[4][DD];               // 16 KB combine buffer
    __shared__ float cml[4][2];
    __shared__ float sm[GROUPS], sl[GROUPS];
    __shared__ int   done;

    const int b    = blockIdx.x >> 4;
    const int g    = blockIdx.x & (GROUPS - 1);
    const int wave = threadIdx.x >> 6;
    const int lane = threadIdx.x & 63;
    const int r0   = g * 32 + wave * RPW;     // <= 504
    const int col  = lane * 4;

    const float* xb = x + (size_t)b * TT * DD;

    float4 v4[4];
#pragma unroll
    for (int j = 0; j < 4; ++j)
        v4[j] = *(const float4*)(v + (size_t)b * DD + j * 256 + col);

    float m = -INFINITY, l = 0.f;
    float4 acc[4] = {make_float4(0,0,0,0), make_float4(0,0,0,0),
                     make_float4(0,0,0,0), make_float4(0,0,0,0)};

#define LOADROW(dst, r) do { const float* _p = xb + (size_t)(r) * DD + col;       \
        dst[0] = *(const float4*)(_p);       dst[1] = *(const float4*)(_p + 256); \
        dst[2] = *(const float4*)(_p + 512); dst[3] = *(const float4*)(_p + 768); } while (0)

    // online-softmax pair step; ca/cb are STATIC buffer names (registers)
#define PROCESS(ca, cb, row) do {                                              \
        float s0 = dot16(v4, ca);                                              \
        float s1 = dot16(v4, cb);                                              \
        _Pragma("unroll")                                                      \
        for (int mm = 1; mm < 64; mm <<= 1) {                                  \
            s0 += __shfl_xor(s0, mm, 64);                                      \
            s1 += __shfl_xor(s1, mm, 64);                                      \
        }                                                                      \
        if ((row)     >= TH) s0 = -INFINITY;                                   \
        if ((row) + 1 >= TH) s1 = -INFINITY;                                   \
        const float mn = fmaxf(m, fmaxf(s0, s1));                              \
        if (mn > m) {                        /* wave-uniform branch */         \
            const float sc = __expf(m - mn);                                   \
            _Pragma("unroll")                                                  \
            for (int j = 0; j < 4; ++j) {                                      \
                acc[j].x *= sc; acc[j].y *= sc;                                \
                acc[j].z *= sc; acc[j].w *= sc;                                \
            }                                                                  \
            l *= sc;                                                           \
            m = mn;                                                            \
        }                                                                      \
        const float e0 = __expf(s0 - m);                                       \
        const float e1 = __expf(s1 - m);                                       \
        l += e0 + e1;                                                          \
        _Pragma("unroll")                                                      \
        for (int j = 0; j < 4; ++j) {                                          \
            acc[j].x += e0 * ca[j].x + e1 * cb[j].x;                           \
            acc[j].y += e0 * ca[j].y + e1 * cb[j].y;                           \
            acc[j].z += e0 * ca[j].z + e1 * cb[j].z;                           \
            acc[j].w += e0 * ca[j].w + e1 * cb[j].w;                           \
        }                                                                      \
    } while (0)

    float4 A0[4], A1[4], B0[4], B1[4];
    // prologue: two pairs in flight
    LOADROW(A0, r0);     LOADROW(A1, r0 + 1);
    LOADROW(B0, r0 + 2); LOADROW(B1, r0 + 3);

    PROCESS(A0, A1, r0);                       // rows r0, r0+1
    LOADROW(A0, r0 + 4); LOADROW(A1, r0 + 5);  // refill A behind B

    PROCESS(B0, B1, r0 + 2);                   // rows r0+2, r0+3
    LOADROW(B0, r0 + 6);
    LOADROW(B1, min(r0 + 7, TH - 1));          // clamp: only row that can OOB

    PROCESS(A0, A1, r0 + 4);                   // rows r0+4, r0+5
    PROCESS(B0, B1, r0 + 6);                   // rows r0+6, r0+7 (masked if >=TH)

#undef LOADROW
#undef PROCESS

    // one cross-wave combine per block
#pragma unroll
    for (int j = 0; j < 4; ++j)
        *(float4*)(&cw[wave][j * 256 + col]) = acc[j];
    if (lane == 0) { cml[wave][0] = m; cml[wave][1] = l; }
    __syncthreads();

    const float M = fmaxf(fmaxf(cml[0][0], cml[1][0]), fmaxf(cml[2][0], cml[3][0]));
    const float w0 = __expf(cml[0][0] - M), w1 = __expf(cml[1][0] - M);
    const float w2 = __expf(cml[2][0] - M), w3 = __expf(cml[3][0] - M);
    const float L = w0 * cml[0][1] + w1 * cml[1][1] + w2 * cml[2][1] + w3 * cml[3][1];

    const int d0 = threadIdx.x * 4;
    {
        const float4 s0 = *(const float4*)(&cw[0][d0]);
        const float4 s1 = *(const float4*)(&cw[1][d0]);
        const float4 s2 = *(const float4*)(&cw[2][d0]);
        const float4 s3 = *(const float4*)(&cw[3][d0]);
        float4 o;
        o.x = w0 * s0.x + w1 * s1.x + w2 * s2.x + w3 * s3.x;
        o.y = w0 * s0.y + w1 * s1.y + w2 * s2.y + w3 * s3.y;
        o.z = w0 * s0.z + w1 * s1.z + w2 * s2.z + w3 * s3.z;
        o.w = w0 * s0.w + w1 * s1.w + w2 * s2.w + w3 * s3.w;
        *(float4*)(partC + ((size_t)b * GROUPS + g) * DD + d0) = o;
    }
    if (threadIdx.x == 0) {
        partML[((size_t)b * GROUPS + g) * 2 + 0] = M;
        partML[((size_t)b * GROUPS + g) * 2 + 1] = L;
    }
    __threadfence();                          // release partials (device scope)
    __syncthreads();
    if (threadIdx.x == 0) {
        const int r = atomicAdd(&cnt[b], 1);
        done = (r == GROUPS - 1);
    }
    __syncthreads();
    if (!done) return;

    // ---- finalize (last block of this batch) ----
    __threadfence();                          // acquire partials
    if (threadIdx.x < GROUPS) {
        sm[threadIdx.x] = partML[((size_t)b * GROUPS + threadIdx.x) * 2 + 0];
        sl[threadIdx.x] = partML[((size_t)b * GROUPS + threadIdx.x) * 2 + 1];
    }
    __syncthreads();

    float Mg = -INFINITY;
#pragma unroll
    for (int g2 = 0; g2 < GROUPS; ++g2) Mg = fmaxf(Mg, sm[g2]);
    float wgt[GROUPS];
    float Lg = 0.f;
#pragma unroll
    for (int g2 = 0; g2 < GROUPS; ++g2) {
        wgt[g2] = __expf(sm[g2] - Mg);
        Lg += wgt[g2] * sl[g2];
    }
    const float invL = 1.f / Lg;

    float4 a = make_float4(0.f, 0.f, 0.f, 0.f);
#pragma unroll
    for (int g2 = 0; g2 < GROUPS; ++g2) {
        const float4 pc = *(const float4*)(partC + ((size_t)b * GROUPS + g2) * DD + d0);
        a.x += wgt[g2] * pc.x; a.y += wgt[g2] * pc.y;
        a.z += wgt[g2] * pc.z; a.w += wgt[g2] * pc.w;
    }
    a.x *= invL; a.y *= invL; a.z *= invL; a.w *= invL;
    *(float4*)(out + (size_t)b * 2048 + d0) = a;

    const float4 xl = *(const float4*)(xb + (size_t)(TT - 1) * DD + d0);
    *(float4*)(out + (size_t)b * 2048 + 1024 + d0) = xl;
}

extern "C" void kernel_launch(void* const* d_in, const int* in_sizes, int n_in,
                              void* d_out, int out_size, void* d_ws, size_t ws_size,
                              hipStream_t stream) {
    const float* x = (const float*)d_in[0];   // (64,512,1024) fp32
    const float* W = (const float*)d_in[1];   // (1024,1024) fp32
    float* out = (float*)d_out;               // (64,2048) fp32

    float* ws     = (float*)d_ws;
    float* v      = ws;                                           // 65536
    float* partC  = ws + 65536;                                   // 1048576
    float* partML = ws + 65536 + (size_t)BB * GROUPS * DD;        // 2048
    int*   cnt    = (int*)(partML + (size_t)BB * GROUPS * 2);     // 64 ints

    k_v<<<256, 256, 0, stream>>>(x, W, v, cnt);
    k_chunk<<<BB * GROUPS, 256, 0, stream>>>(x, v, partC, partML, cnt, out);
}

// Round 9
// 198.806 us; speedup vs baseline: 1.0531x; 1.0414x over previous
//
#include <hip/hip_runtime.h>
#include <math.h>

// Problem: B=64, T=512, D=1024.
//   v[b,d]     = sum_e W[d,e] * x[b,T-1,e]
//   scores[b,t]= sum_d x[b,t,d] * v[b,d]          (t in 0..510)
//   alpha      = softmax_t(scores)
//   c[b,d]     = sum_t alpha[b,t] * x[b,t,d]
//   out[b]     = concat(c[b,:], x[b,T-1,:])       (64 x 2048 fp32)
//
// HISTORY (R5-R7 regression): passing local float4[4] buffers to a
// __forceinline__ helper (dot16) made them address-taken -> scratch
// (VGPR_Count=64, 210us). Hot-loop data is NAMED float4 scalars via
// token-pasting macros; pasted names parenthesized: (ca##0).x  — plain
// ca##0.x lexes "0.x" as one pp-number and breaks the paste (R8 bug).

#define BB 64
#define TT 512
#define DD 1024
#define TH 511           // valid history rows: 0..510
#define GROUPS 16        // blocks per batch
#define RPW 8            // rows per wave (4 waves * 8 = 32 rows per block)

// workspace (floats):
//   v      : [BB][DD]          off 0
//   partC  : [BB][GROUPS][DD]  off 65536
//   partML : [BB][GROUPS][2]   off 1114112
//   cnt    : [BB] ints         off 1116160

// ---------------- kernel 1: v = x_last @ W^T (+ zero finalize counters) ----
// 256 blocks x 4 waves; wave = 4 d-rows (W stationary) x 16 batches.
__global__ __launch_bounds__(256, 4) void k_v(const float* __restrict__ x,
                                              const float* __restrict__ W,
                                              float* __restrict__ v,
                                              int* __restrict__ cnt) {
    if (blockIdx.x == 0 && threadIdx.x < BB) cnt[threadIdx.x] = 0;

    const int wave = threadIdx.x >> 6;
    const int lane = threadIdx.x & 63;
    const int wg   = blockIdx.x * 4 + wave;   // 0..1023
    const int d0   = (wg >> 2) * 4;           // 256 d-quads
    const int bg   = wg & 3;                  // 4 batch-groups of 16

    float4 w4[4][4];
#pragma unroll
    for (int k = 0; k < 4; ++k)
#pragma unroll
        for (int j = 0; j < 4; ++j)
            w4[k][j] = *(const float4*)(W + (size_t)(d0 + k) * DD + j * 256 + lane * 4);

    float res = 0.f;                          // lane l -> (b = bg*16+(l>>2), d = d0+(l&3))
#pragma unroll 4
    for (int i = 0; i < 16; ++i) {
        const int b = bg * 16 + i;
        const float* xl = x + ((size_t)b * TT + (TT - 1)) * DD;
        float4 x4[4];
#pragma unroll
        for (int j = 0; j < 4; ++j)
            x4[j] = *(const float4*)(xl + j * 256 + lane * 4);
#pragma unroll
        for (int k = 0; k < 4; ++k) {
            float p = 0.f;
#pragma unroll
            for (int j = 0; j < 4; ++j)
                p += w4[k][j].x * x4[j].x + w4[k][j].y * x4[j].y +
                     w4[k][j].z * x4[j].z + w4[k][j].w * x4[j].w;
#pragma unroll
            for (int m = 1; m < 64; m <<= 1) p += __shfl_xor(p, m, 64);
            if (lane == i * 4 + k) res = p;
        }
    }
    v[(size_t)(bg * 16 + (lane >> 2)) * DD + d0 + (lane & 3)] = res;
}

// ---------------- kernel 2: wave-autonomous flash + fused finalize ---------
// 1024 blocks (64 b x 16 groups), 256 thr. Wave: 8 rows in pairs, online
// softmax fully in NAMED registers, depth-2-pair prefetch, no barriers in
// hot loop. Last block per batch combines the 16 partials and writes out.
__global__ __launch_bounds__(256, 3) void k_chunk(const float* __restrict__ x,
                                                  const float* __restrict__ v,
                                                  float* __restrict__ partC,
                                                  float* __restrict__ partML,
                                                  int* __restrict__ cnt,
                                                  float* __restrict__ out) {
    __shared__ float cw[4][DD];               // 16 KB combine buffer
    __shared__ float cml[4][2];
    __shared__ float sm[GROUPS], sl[GROUPS];
    __shared__ int   done;

    const int b    = blockIdx.x >> 4;
    const int g    = blockIdx.x & (GROUPS - 1);
    const int wave = threadIdx.x >> 6;
    const int lane = threadIdx.x & 63;
    const int r0   = g * 32 + wave * RPW;     // <= 504
    const int col  = lane * 4;

    const float* xb = x + (size_t)b * TT * DD;

    const float* vb = v + (size_t)b * DD + col;
    const float4 vv0 = *(const float4*)(vb);
    const float4 vv1 = *(const float4*)(vb + 256);
    const float4 vv2 = *(const float4*)(vb + 512);
    const float4 vv3 = *(const float4*)(vb + 768);

    float m = -INFINITY, l = 0.f;
    float4 acc0 = make_float4(0,0,0,0), acc1 = make_float4(0,0,0,0);
    float4 acc2 = make_float4(0,0,0,0), acc3 = make_float4(0,0,0,0);

    // named row buffers: A pair (a0_,a1_) and B pair (b0_,b1_), 4 float4 each
    float4 a0_0, a0_1, a0_2, a0_3,  a1_0, a1_1, a1_2, a1_3;
    float4 b0_0, b0_1, b0_2, b0_3,  b1_0, b1_1, b1_2, b1_3;

#define LOADROW(nm, r) do { const float* _p = xb + (size_t)(r) * DD + col;          \
        nm##0 = *(const float4*)(_p);       nm##1 = *(const float4*)(_p + 256);     \
        nm##2 = *(const float4*)(_p + 512); nm##3 = *(const float4*)(_p + 768); } while (0)

#define PROC(ca, cb, row) do {                                                      \
    float s0 = vv0.x*(ca##0).x + vv0.y*(ca##0).y + vv0.z*(ca##0).z + vv0.w*(ca##0).w \
             + vv1.x*(ca##1).x + vv1.y*(ca##1).y + vv1.z*(ca##1).z + vv1.w*(ca##1).w \
             + vv2.x*(ca##2).x + vv2.y*(ca##2).y + vv2.z*(ca##2).z + vv2.w*(ca##2).w \
             + vv3.x*(ca##3).x + vv3.y*(ca##3).y + vv3.z*(ca##3).z + vv3.w*(ca##3).w; \
    float s1 = vv0.x*(cb##0).x + vv0.y*(cb##0).y + vv0.z*(cb##0).z + vv0.w*(cb##0).w \
             + vv1.x*(cb##1).x + vv1.y*(cb##1).y + vv1.z*(cb##1).z + vv1.w*(cb##1).w \
             + vv2.x*(cb##2).x + vv2.y*(cb##2).y + vv2.z*(cb##2).z + vv2.w*(cb##2).w \
             + vv3.x*(cb##3).x + vv3.y*(cb##3).y + vv3.z*(cb##3).z + vv3.w*(cb##3).w; \
    _Pragma("unroll")                                                               \
    for (int mm = 1; mm < 64; mm <<= 1) {                                           \
        s0 += __shfl_xor(s0, mm, 64);                                               \
        s1 += __shfl_xor(s1, mm, 64);                                               \
    }                                                                               \
    if ((row)     >= TH) s0 = -INFINITY;                                            \
    if ((row) + 1 >= TH) s1 = -INFINITY;                                            \
    const float mn = fmaxf(m, fmaxf(s0, s1));                                       \
    if (mn > m) {                         /* wave-uniform branch */                 \
        const float sc = __expf(m - mn);  /* first pair: exp(-inf)=0 */             \
        acc0.x*=sc; acc0.y*=sc; acc0.z*=sc; acc0.w*=sc;                             \
        acc1.x*=sc; acc1.y*=sc; acc1.z*=sc; acc1.w*=sc;                             \
        acc2.x*=sc; acc2.y*=sc; acc2.z*=sc; acc2.w*=sc;                             \
        acc3.x*=sc; acc3.y*=sc; acc3.z*=sc; acc3.w*=sc;                             \
        l *= sc; m = mn;                                                            \
    }                                                                               \
    const float e0 = __expf(s0 - m);                                                \
    const float e1 = __expf(s1 - m);                                                \
    l += e0 + e1;                                                                   \
    acc0.x += e0*(ca##0).x + e1*(cb##0).x;  acc0.y += e0*(ca##0).y + e1*(cb##0).y;  \
    acc0.z += e0*(ca##0).z + e1*(cb##0).z;  acc0.w += e0*(ca##0).w + e1*(cb##0).w;  \
    acc1.x += e0*(ca##1).x + e1*(cb##1).x;  acc1.y += e0*(ca##1).y + e1*(cb##1).y;  \
    acc1.z += e0*(ca##1).z + e1*(cb##1).z;  acc1.w += e0*(ca##1).w + e1*(cb##1).w;  \
    acc2.x += e0*(ca##2).x + e1*(cb##2).x;  acc2.y += e0*(ca##2).y + e1*(cb##2).y;  \
    acc2.z += e0*(ca##2).z + e1*(cb##2).z;  acc2.w += e0*(ca##2).w + e1*(cb##2).w;  \
    acc3.x += e0*(ca##3).x + e1*(cb##3).x;  acc3.y += e0*(ca##3).y + e1*(cb##3).y;  \
    acc3.z += e0*(ca##3).z + e1*(cb##3).z;  acc3.w += e0*(ca##3).w + e1*(cb##3).w;  \
} while (0)

    // prologue: two pairs in flight
    LOADROW(a0_, r0);     LOADROW(a1_, r0 + 1);
    LOADROW(b0_, r0 + 2); LOADROW(b1_, r0 + 3);

    PROC(a0_, a1_, r0);                        // rows r0, r0+1
    LOADROW(a0_, r0 + 4); LOADROW(a1_, r0 + 5);

    PROC(b0_, b1_, r0 + 2);                    // rows r0+2, r0+3
    LOADROW(b0_, r0 + 6);
    LOADROW(b1_, min(r0 + 7, TH - 1));         // clamp: only row that can OOB

    PROC(a0_, a1_, r0 + 4);                    // rows r0+4, r0+5
    PROC(b0_, b1_, r0 + 6);                    // rows r0+6, r0+7 (masked if >=TH)

#undef LOADROW
#undef PROC

    // one cross-wave combine per block
    *(float4*)(&cw[wave][0 * 256 + col]) = acc0;
    *(float4*)(&cw[wave][1 * 256 + col]) = acc1;
    *(float4*)(&cw[wave][2 * 256 + col]) = acc2;
    *(float4*)(&cw[wave][3 * 256 + col]) = acc3;
    if (lane == 0) { cml[wave][0] = m; cml[wave][1] = l; }
    __syncthreads();

    const float M = fmaxf(fmaxf(cml[0][0], cml[1][0]), fmaxf(cml[2][0], cml[3][0]));
    const float w0 = __expf(cml[0][0] - M), w1 = __expf(cml[1][0] - M);
    const float w2 = __expf(cml[2][0] - M), w3 = __expf(cml[3][0] - M);
    const float L = w0 * cml[0][1] + w1 * cml[1][1] + w2 * cml[2][1] + w3 * cml[3][1];

    const int d0 = threadIdx.x * 4;
    {
        const float4 s0 = *(const float4*)(&cw[0][d0]);
        const float4 s1 = *(const float4*)(&cw[1][d0]);
        const float4 s2 = *(const float4*)(&cw[2][d0]);
        const float4 s3 = *(const float4*)(&cw[3][d0]);
        float4 o;
        o.x = w0 * s0.x + w1 * s1.x + w2 * s2.x + w3 * s3.x;
        o.y = w0 * s0.y + w1 * s1.y + w2 * s2.y + w3 * s3.y;
        o.z = w0 * s0.z + w1 * s1.z + w2 * s2.z + w3 * s3.z;
        o.w = w0 * s0.w + w1 * s1.w + w2 * s2.w + w3 * s3.w;
        *(float4*)(partC + ((size_t)b * GROUPS + g) * DD + d0) = o;
    }
    if (threadIdx.x == 0) {
        partML[((size_t)b * GROUPS + g) * 2 + 0] = M;
        partML[((size_t)b * GROUPS + g) * 2 + 1] = L;
    }
    __threadfence();                          // release partials (device scope)
    __syncthreads();
    if (threadIdx.x == 0) {
        const int r = atomicAdd(&cnt[b], 1);
        done = (r == GROUPS - 1);
    }
    __syncthreads();
    if (!done) return;

    // ---- finalize (last block of this batch) ----
    __threadfence();                          // acquire partials
    if (threadIdx.x < GROUPS) {
        sm[threadIdx.x] = partML[((size_t)b * GROUPS + threadIdx.x) * 2 + 0];
        sl[threadIdx.x] = partML[((size_t)b * GROUPS + threadIdx.x) * 2 + 1];
    }
    __syncthreads();

    float Mg = -INFINITY;
#pragma unroll
    for (int g2 = 0; g2 < GROUPS; ++g2) Mg = fmaxf(Mg, sm[g2]);
    float Lg = 0.f;
#pragma unroll
    for (int g2 = 0; g2 < GROUPS; ++g2) Lg += __expf(sm[g2] - Mg) * sl[g2];
    const float invL = 1.f / Lg;

    float4 a = make_float4(0.f, 0.f, 0.f, 0.f);
#pragma unroll
    for (int g2 = 0; g2 < GROUPS; ++g2) {
        const float wgt = __expf(sm[g2] - Mg);
        const float4 pc = *(const float4*)(partC + ((size_t)b * GROUPS + g2) * DD + d0);
        a.x += wgt * pc.x; a.y += wgt * pc.y;
        a.z += wgt * pc.z; a.w += wgt * pc.w;
    }
    a.x *= invL; a.y *= invL; a.z *= invL; a.w *= invL;
    *(float4*)(out + (size_t)b * 2048 + d0) = a;

    const float4 xl = *(const float4*)(xb + (size_t)(TT - 1) * DD + d0);
    *(float4*)(out + (size_t)b * 2048 + 1024 + d0) = xl;
}

extern "C" void kernel_launch(void* const* d_in, const int* in_sizes, int n_in,
                              void* d_out, int out_size, void* d_ws, size_t ws_size,
                              hipStream_t stream) {
    const float* x = (const float*)d_in[0];   // (64,512,1024) fp32
    const float* W = (const float*)d_in[1];   // (1024,1024) fp32
    float* out = (float*)d_out;               // (64,2048) fp32

    float* ws     = (float*)d_ws;
    float* v      = ws;                                           // 65536
    float* partC  = ws + 65536;                                   // 1048576
    float* partML = ws + 65536 + (size_t)BB * GROUPS * DD;        // 2048
    int*   cnt    = (int*)(partML + (size_t)BB * GROUPS * 2);     // 64 ints

    k_v<<<256, 256, 0, stream>>>(x, W, v, cnt);
    k_chunk<<<BB * GROUPS, 256, 0, stream>>>(x, v, partC, partML, cnt, out);
}

// Round 10
// 51.978 us; speedup vs baseline: 4.0279x; 3.8248x over previous
//
#include <hip/hip_runtime.h>
#include <math.h>

// Problem: B=64, T=512, D=1024.
//   v[b,d]     = sum_e W[d,e] * x[b,T-1,e]
//   scores[b,t]= sum_d x[b,t,d] * v[b,d]          (t in 0..510)
//   alpha      = softmax_t(scores)
//   c[b,d]     = sum_t alpha[b,t] * x[b,t,d]
//   out[b]     = concat(c[b,:], x[b,T-1,:])       (64 x 2048 fp32)
//
// HISTORY:
//  R4 (3 kernels, no fences)            = 49.3 us  <- proven baseline
//  R5-R9 (fused finalize w/ __threadfence + atomic) = ~200 us: agent-scope
//    fence => per-XCD L2 writeback/invalidate per block, ~fixed 270us cost
//    (warm replays moving 4.8MB took as long as cold ones moving 68MB).
//    Cross-XCD visibility REQUIRES that fence -> fused finalize is
//    structurally wrong on CDNA4. Reverted to 3 kernels.
//  This round: GROUPS 16->32 (2048 blocks, 16 rows/block) for 2x resident
//    waves in the streaming kernel.

#define BB 64
#define TT 512
#define DD 1024
#define TH 511           // valid history rows: 0..510
#define GROUPS 32        // blocks per batch
#define RPW 4            // rows per wave (4 waves * 4 = 16 rows per block)

// workspace (floats):
//   v      : [BB][DD]          off 0            (65536)
//   partC  : [BB][GROUPS][DD]  off 65536        (2097152, 8 MB)
//   partML : [BB][GROUPS][2]   off 2162688      (4096)

// ---------------- kernel 1: v = x_last @ W^T -------------------------------
// 256 blocks x 4 waves; wave = 4 d-rows (W stationary, 64 VGPR) x 16 batches.
__global__ __launch_bounds__(256, 4) void k_v(const float* __restrict__ x,
                                              const float* __restrict__ W,
                                              float* __restrict__ v) {
    const int wave = threadIdx.x >> 6;
    const int lane = threadIdx.x & 63;
    const int wg   = blockIdx.x * 4 + wave;   // 0..1023
    const int d0   = (wg >> 2) * 4;           // 256 d-quads
    const int bg   = wg & 3;                  // 4 batch-groups of 16

    float4 w4[4][4];
#pragma unroll
    for (int k = 0; k < 4; ++k)
#pragma unroll
        for (int j = 0; j < 4; ++j)
            w4[k][j] = *(const float4*)(W + (size_t)(d0 + k) * DD + j * 256 + lane * 4);

    float res = 0.f;                          // lane l -> (b = bg*16+(l>>2), d = d0+(l&3))
#pragma unroll 4
    for (int i = 0; i < 16; ++i) {
        const int b = bg * 16 + i;
        const float* xl = x + ((size_t)b * TT + (TT - 1)) * DD;
        float4 x4[4];
#pragma unroll
        for (int j = 0; j < 4; ++j)
            x4[j] = *(const float4*)(xl + j * 256 + lane * 4);
#pragma unroll
        for (int k = 0; k < 4; ++k) {
            float p = 0.f;
#pragma unroll
            for (int j = 0; j < 4; ++j)
                p += w4[k][j].x * x4[j].x + w4[k][j].y * x4[j].y +
                     w4[k][j].z * x4[j].z + w4[k][j].w * x4[j].w;
#pragma unroll
            for (int m = 1; m < 64; m <<= 1) p += __shfl_xor(p, m, 64);
            if (lane == i * 4 + k) res = p;
        }
    }
    v[(size_t)(bg * 16 + (lane >> 2)) * DD + d0 + (lane & 3)] = res;
}

// ---------------- kernel 2: wave-autonomous flash chunk (R4 style) ---------
// 2048 blocks (64 b x 32 groups), 256 thr. Each wave: 4 rows, online softmax
// in registers, one-row-ahead prefetch, NO barriers in hot loop. Arrays use
// only compile-time indices (unrolled) - proven register-resident in R4.
__global__ __launch_bounds__(256, 4) void k_chunk(const float* __restrict__ x,
                                                  const float* __restrict__ v,
                                                  float* __restrict__ partC,
                                                  float* __restrict__ partML) {
    __shared__ float cw[4][DD];               // 16 KB combine buffer
    __shared__ float cml[4][2];

    const int b    = blockIdx.x >> 5;         // / GROUPS
    const int g    = blockIdx.x & (GROUPS - 1);
    const int wave = threadIdx.x >> 6;
    const int lane = threadIdx.x & 63;
    const int r0   = g * 16 + wave * RPW;     // <= 508, first row always valid
    const int col  = lane * 4;

    const float* xb = x + (size_t)b * TT * DD;

    float4 v4[4];
#pragma unroll
    for (int j = 0; j < 4; ++j)
        v4[j] = *(const float4*)(v + (size_t)b * DD + j * 256 + col);

    float4 xa[4], xn[4];
#pragma unroll
    for (int j = 0; j < 4; ++j)
        xa[j] = *(const float4*)(xb + (size_t)r0 * DD + j * 256 + col);

    float m = -INFINITY, l = 0.f;
    float4 acc[4] = {make_float4(0,0,0,0), make_float4(0,0,0,0),
                     make_float4(0,0,0,0), make_float4(0,0,0,0)};

#pragma unroll
    for (int i = 0; i < RPW; ++i) {
        // prefetch next row (clamped address; validity handled via score)
        if (i < RPW - 1) {
            const int rn = min(r0 + i + 1, TH - 1);
#pragma unroll
            for (int j = 0; j < 4; ++j)
                xn[j] = *(const float4*)(xb + (size_t)rn * DD + j * 256 + col);
        }

        // score of current row
        float s = 0.f;
#pragma unroll
        for (int j = 0; j < 4; ++j)
            s += v4[j].x * xa[j].x + v4[j].y * xa[j].y +
                 v4[j].z * xa[j].z + v4[j].w * xa[j].w;
#pragma unroll
        for (int mm = 1; mm < 64; mm <<= 1) s += __shfl_xor(s, mm, 64);
        if (r0 + i >= TH) s = -INFINITY;      // invalid tail row -> e = 0

        const float mnew = fmaxf(m, s);
        if (mnew > m) {                        // wave-uniform branch
            const float scale = __expf(m - mnew);
#pragma unroll
            for (int j = 0; j < 4; ++j) {
                acc[j].x *= scale; acc[j].y *= scale;
                acc[j].z *= scale; acc[j].w *= scale;
            }
            l *= scale;
            m = mnew;
        }
        const float e = __expf(s - m);
        l += e;
#pragma unroll
        for (int j = 0; j < 4; ++j) {
            acc[j].x += e * xa[j].x; acc[j].y += e * xa[j].y;
            acc[j].z += e * xa[j].z; acc[j].w += e * xa[j].w;
        }
        if (i < RPW - 1) {
#pragma unroll
            for (int j = 0; j < 4; ++j) xa[j] = xn[j];
        }
    }

    // one cross-wave combine per block
#pragma unroll
    for (int j = 0; j < 4; ++j)
        *(float4*)(&cw[wave][j * 256 + col]) = acc[j];
    if (lane == 0) { cml[wave][0] = m; cml[wave][1] = l; }
    __syncthreads();

    const float M = fmaxf(fmaxf(cml[0][0], cml[1][0]), fmaxf(cml[2][0], cml[3][0]));
    const float w0 = __expf(cml[0][0] - M), w1 = __expf(cml[1][0] - M);
    const float w2 = __expf(cml[2][0] - M), w3 = __expf(cml[3][0] - M);
    const float L = w0 * cml[0][1] + w1 * cml[1][1] + w2 * cml[2][1] + w3 * cml[3][1];

    const int d0 = threadIdx.x * 4;
    const float4 s0 = *(const float4*)(&cw[0][d0]);
    const float4 s1 = *(const float4*)(&cw[1][d0]);
    const float4 s2 = *(const float4*)(&cw[2][d0]);
    const float4 s3 = *(const float4*)(&cw[3][d0]);
    float4 o;
    o.x = w0 * s0.x + w1 * s1.x + w2 * s2.x + w3 * s3.x;
    o.y = w0 * s0.y + w1 * s1.y + w2 * s2.y + w3 * s3.y;
    o.z = w0 * s0.z + w1 * s1.z + w2 * s2.z + w3 * s3.z;
    o.w = w0 * s0.w + w1 * s1.w + w2 * s2.w + w3 * s3.w;
    *(float4*)(partC + ((size_t)b * GROUPS + g) * DD + d0) = o;
    if (threadIdx.x == 0) {
        partML[((size_t)b * GROUPS + g) * 2 + 0] = M;
        partML[((size_t)b * GROUPS + g) * 2 + 1] = L;
    }
}

// ---------------- kernel 3: combine partials, divide, append x_last --------
// 256 blocks: (b, quarter-of-d). One float per thread; weights in LDS.
__global__ __launch_bounds__(256) void k_final(const float* __restrict__ x,
                                               const float* __restrict__ partC,
                                               const float* __restrict__ partML,
                                               float* __restrict__ out) {
    const int b = blockIdx.x >> 2;
    const int q = blockIdx.x & 3;
    __shared__ float wgt[GROUPS];
    __shared__ float lsh;

    if (threadIdx.x < GROUPS) {
        float M = -INFINITY;
        for (int cc = 0; cc < GROUPS; ++cc)
            M = fmaxf(M, partML[((size_t)b * GROUPS + cc) * 2]);
        wgt[threadIdx.x] = __expf(partML[((size_t)b * GROUPS + threadIdx.x) * 2] - M);
    }
    __syncthreads();
    if (threadIdx.x == 0) {
        float L = 0.f;
        for (int cc = 0; cc < GROUPS; ++cc)
            L += partML[((size_t)b * GROUPS + cc) * 2 + 1] * wgt[cc];
        lsh = 1.f / L;
    }
    __syncthreads();
    const float invL = lsh;

    const int d = q * 256 + threadIdx.x;
    float acc = 0.f;
#pragma unroll 8
    for (int cc = 0; cc < GROUPS; ++cc)
        acc += wgt[cc] * partC[((size_t)b * GROUPS + cc) * DD + d];
    out[(size_t)b * 2048 + d] = acc * invL;
    out[(size_t)b * 2048 + 1024 + d] = x[((size_t)b * TT + (TT - 1)) * DD + d];
}

extern "C" void kernel_launch(void* const* d_in, const int* in_sizes, int n_in,
                              void* d_out, int out_size, void* d_ws, size_t ws_size,
                              hipStream_t stream) {
    const float* x = (const float*)d_in[0];   // (64,512,1024) fp32
    const float* W = (const float*)d_in[1];   // (1024,1024) fp32
    float* out = (float*)d_out;               // (64,2048) fp32

    float* ws     = (float*)d_ws;             // ~8.5 MB
    float* v      = ws;                                           // 65536
    float* partC  = ws + 65536;                                   // 2097152
    float* partML = ws + 65536 + (size_t)BB * GROUPS * DD;        // 4096

    k_v<<<256, 256, 0, stream>>>(x, W, v);
    k_chunk<<<BB * GROUPS, 256, 0, stream>>>(x, v, partC, partML);
    k_final<<<BB * 4, 256, 0, stream>>>(x, partC, partML, out);
}